// Round 10
// baseline (325.085 us; speedup 1.0000x reference)
//
#include <hip/hip_runtime.h>

#define BLK 256
#define WBITS 13          // idx-window = 8192 edges (32KB per ei half)
#define W1CAPS 2432       // per-(step,window) cap (mean 2048, +8 sigma, 64-line mult)
#define CAPB 4608         // per-(step,dst-bucket) cap (mean 4096, +8 sigma)
#define MAXNW 1024
#define MAXNBD 512
#define OVFN 65536
#define IPTA 16           // k_win: 512 thr * 16 = 8192 entries/block
#define NSL 20            // k_bin2: 4 windows * ceil(2432/512)=5 slots

// ---------------- init: copy compact x (n,10) into strided h (n,16) --------
__global__ void k_init_h(const float* __restrict__ x, float* __restrict__ h, int n) {
    int total = n * 16;
    int gs = gridDim.x * blockDim.x;
    for (int i = blockIdx.x * blockDim.x + threadIdx.x; i < total; i += gs) {
        int row = i >> 4, col = i & 15;
        h[i] = (col < 10) ? x[row * 10 + col] : 0.0f;
    }
}

// ---------------- pass A: bin order entries by (step, idx-window) ----------
// step-pure blocks: record = bare idx
__global__ __launch_bounds__(512) void k_win(const int* __restrict__ orders,
                                             int epo, int NW, int TPS,
                                             int* __restrict__ gcnt1,
                                             unsigned* __restrict__ recs1,
                                             int* __restrict__ ovf1_cnt,
                                             unsigned* __restrict__ ovf1) {
    __shared__ int bcnt[MAXNW];
    __shared__ int gbase[MAXNW];
    int t = threadIdx.x;
    int st = blockIdx.x / TPS;
    int tb = blockIdx.x % TPS;
    for (int i = t; i < NW; i += 512) bcnt[i] = 0;
    __syncthreads();

    const int* ord = orders + (size_t)st * epo + (size_t)tb * (512 * IPTA);
    int lim = epo - tb * (512 * IPTA);        // entries in this block's tile

    int idxs[IPTA]; int rr[IPTA];
    #pragma unroll
    for (int q = 0; q < IPTA; ++q) {
        int e = q * 512 + t;
        idxs[q] = (e < lim) ? ord[e] : -1;
    }
    #pragma unroll
    for (int q = 0; q < IPTA; ++q)
        rr[q] = (idxs[q] >= 0) ? atomicAdd(&bcnt[idxs[q] >> WBITS], 1) : 0;
    __syncthreads();
    for (int k = t; k < NW; k += 512) {
        int c = bcnt[k];
        gbase[k] = c ? atomicAdd(&gcnt1[st * NW + k], c) : 0;
    }
    __syncthreads();
    #pragma unroll
    for (int q = 0; q < IPTA; ++q) {
        if (idxs[q] >= 0) {
            int w = idxs[q] >> WBITS;
            int pos = gbase[w] + rr[q];
            if (pos < W1CAPS)
                recs1[((size_t)st * NW + w) * W1CAPS + pos] = (unsigned)idxs[q];
            else {
                int o = atomicAdd(ovf1_cnt, 1);
                if (o < OVFN) ovf1[o] = ((unsigned)st << 23) | (unsigned)idxs[q];
            }
        }
    }
}

// ---------------- pass B: step-pure, 4 windows/block, reg-resident ---------
// bin by d>>8 into (st, dbkt) streams; runs of ~21 records (>= 1 full line).
__global__ __launch_bounds__(512) void k_bin2(const int* __restrict__ ei, int ne,
                                              const int* __restrict__ gcnt1,
                                              const unsigned* __restrict__ recs1,
                                              int NW, int NWG, int NBD,
                                              int* __restrict__ gcnt2,
                                              unsigned* __restrict__ recs2,
                                              int* __restrict__ ovf2_cnt,
                                              int2* __restrict__ ovf2) {
    __shared__ int cnt2[MAXNBD];
    __shared__ int gbase[MAXNBD];
    int t = threadIdx.x;
    int st = blockIdx.x / NWG;
    int wg = blockIdx.x % NWG;
    for (int i = t; i < NBD; i += 512) cnt2[i] = 0;
    __syncthreads();

    int segc[4];
    #pragma unroll
    for (int g = 0; g < 4; ++g) {
        int w = wg * 4 + g;
        int c = (w < NW) ? gcnt1[st * NW + w] : 0;
        segc[g] = (c < W1CAPS) ? c : W1CAPS;
    }

    // 1) stage record idx (independent stream loads)
    int idxs[NSL];
    #pragma unroll
    for (int g = 0; g < 4; ++g) {
        const unsigned* strm = recs1 + ((size_t)st * NW + wg * 4 + g) * W1CAPS;
        #pragma unroll
        for (int q = 0; q < 5; ++q) {
            int r = q * 512 + t;
            idxs[g * 5 + q] = (r < segc[g]) ? (int)strm[r] : -1;
        }
    }
    // 2) independent d gathers (128KB window, L2-resident)
    int dv[NSL];
    #pragma unroll
    for (int s2 = 0; s2 < NSL; ++s2)
        dv[s2] = (idxs[s2] >= 0) ? ei[idxs[s2]] : 0;
    // 3) LDS rank; meta = (d<<14)|rk  (d<2^17, rk<9728<2^14, total 31 bits)
    int meta[NSL];
    #pragma unroll
    for (int s2 = 0; s2 < NSL; ++s2) {
        meta[s2] = -1;
        if (idxs[s2] >= 0) {
            int rk = atomicAdd(&cnt2[dv[s2] >> 8], 1);
            meta[s2] = (dv[s2] << 14) | rk;
        }
    }
    __syncthreads();
    // 4) one reservation per touched key
    for (int k = t; k < NBD; k += 512) {
        int c = cnt2[k];
        gbase[k] = c ? atomicAdd(&gcnt2[st * NBD + k], c) : 0;
    }
    __syncthreads();
    // 5) gather s (L2-hot window) + scatter
    #pragma unroll
    for (int s2 = 0; s2 < NSL; ++s2) {
        if (meta[s2] >= 0) {
            int s = ei[(size_t)ne + idxs[s2]];
            int d = meta[s2] >> 14, rk = meta[s2] & 16383;
            int key = d >> 8;
            int pos = gbase[key] + rk;
            unsigned r2 = ((unsigned)(d & 255) << 20) | (unsigned)s;
            if (pos < CAPB)
                recs2[((size_t)st * NBD + key) * CAPB + pos] = r2;
            else {
                int o = atomicAdd(ovf2_cnt, 1);
                if (o < OVFN) ovf2[o] = make_int2((st << 18) | d, s);
            }
        }
    }
}

// ---------------- aggregate via in-LDS counting sort, register sums --------
#define IPTG ((CAPB + 511) / 512)    // 9
template<bool FINAL>
__global__ __launch_bounds__(512) void k_agg2(const float* __restrict__ h_cur,
                                              float* __restrict__ h_next,
                                              const int* __restrict__ gcnt2_st,
                                              const unsigned* __restrict__ recs2_st,
                                              const float* __restrict__ w_mp,
                                              const float* __restrict__ b_mp,
                                              const float* __restrict__ w_out,
                                              const float* __restrict__ b_out,
                                              float* __restrict__ out, int n) {
    __shared__ unsigned srt[CAPB];
    __shared__ int cnts[256];
    __shared__ int sc[256];
    __shared__ int offs[257];
    __shared__ float part[256 * 10];
    __shared__ float Wa[100], Wb[100], Bm[10];
    __shared__ float Wo[100], Bo[10];
    int t = threadIdx.x;
    if (t < 100) {
        int k = t / 10, j = t - k * 10;
        float w1 = w_mp[k * 20 + j];
        float w2 = w_mp[k * 20 + 10 + j];
        Wa[t] = w1 - w2; Wb[t] = w2;
        if (FINAL) Wo[t] = w_out[t];
    }
    if (t < 10) { Bm[t] = b_mp[t]; if (FINAL) Bo[t] = b_out[t]; }
    if (t < 256) cnts[t] = 0;
    __syncthreads();

    int bkt = blockIdx.x;
    int cnt = gcnt2_st[bkt];
    if (cnt > CAPB) cnt = CAPB;
    const unsigned* strm = recs2_st + (size_t)bkt * CAPB;

    unsigned myrec[IPTG];
    #pragma unroll
    for (int q = 0; q < IPTG; ++q) {
        int r = q * 512 + t;
        myrec[q] = 0xFFFFFFFFu;
        if (r < cnt) {
            unsigned rec = strm[r];
            myrec[q] = rec;
            atomicAdd(&cnts[rec >> 20], 1);
        }
    }
    __syncthreads();

    if (t < 256) sc[t] = cnts[t];
    __syncthreads();
    for (int off = 1; off < 256; off <<= 1) {
        int v = (t < 256 && t >= off) ? sc[t - off] : 0;
        __syncthreads();
        if (t < 256) sc[t] += v;
        __syncthreads();
    }
    if (t < 256) offs[t + 1] = sc[t];
    if (t == 0) offs[0] = 0;
    __syncthreads();
    if (t < 256) cnts[t] = offs[t];
    __syncthreads();

    #pragma unroll
    for (int q = 0; q < IPTG; ++q) {
        if (myrec[q] != 0xFFFFFFFFu) {
            int pos = atomicAdd(&cnts[myrec[q] >> 20], 1);
            srt[pos] = myrec[q];
        }
    }
    __syncthreads();

    int node = t & 255, half = t >> 8;
    int b0 = offs[node], m = offs[node + 1] - b0;
    float S[10] = {0,0,0,0,0,0,0,0,0,0};
    for (int p = b0 + half; p < b0 + m; p += 2) {
        int s = (int)(srt[p] & 0xFFFFFu);
        const float* pj = h_cur + (size_t)s * 16;
        float4 a0 = *(const float4*)(pj);
        float4 a1 = *(const float4*)(pj + 4);
        float2 a2 = *(const float2*)(pj + 8);
        S[0] += a0.x; S[1] += a0.y; S[2] += a0.z; S[3] += a0.w;
        S[4] += a1.x; S[5] += a1.y; S[6] += a1.z; S[7] += a1.w;
        S[8] += a2.x; S[9] += a2.y;
    }
    if (half == 1) {
        #pragma unroll
        for (int j = 0; j < 10; ++j) part[node * 10 + j] = S[j];
    }
    __syncthreads();
    if (half == 0) {
        int i = bkt * 256 + node;
        if (i < n) {
            #pragma unroll
            for (int j = 0; j < 10; ++j) S[j] += part[node * 10 + j];
            const float* pi = h_cur + (size_t)i * 16;
            float4 x0 = *(const float4*)(pi);
            float4 x1 = *(const float4*)(pi + 4);
            float2 x2 = *(const float2*)(pi + 8);
            float xi[10] = {x0.x, x0.y, x0.z, x0.w, x1.x, x1.y, x1.z, x1.w, x2.x, x2.y};
            float deg = (float)m;
            float o[10];
            #pragma unroll
            for (int k = 0; k < 10; ++k) {
                float ma = Bm[k];
                float mb = 0.0f;
                #pragma unroll
                for (int j = 0; j < 10; ++j) {
                    ma += Wa[k * 10 + j] * xi[j];
                    mb += Wb[k * 10 + j] * S[j];
                }
                o[k] = xi[k] + deg * ma + mb;
            }
            if (FINAL) {
                float q2[10];
                #pragma unroll
                for (int k = 0; k < 10; ++k) {
                    float m2 = Bo[k];
                    #pragma unroll
                    for (int j = 0; j < 10; ++j) m2 += Wo[k * 10 + j] * o[j];
                    q2[k] = m2;
                }
                float* po = out + (size_t)i * 10;
                *(float2*)(po)     = make_float2(q2[0], q2[1]);
                *(float2*)(po + 2) = make_float2(q2[2], q2[3]);
                *(float2*)(po + 4) = make_float2(q2[4], q2[5]);
                *(float2*)(po + 6) = make_float2(q2[6], q2[7]);
                *(float2*)(po + 8) = make_float2(q2[8], q2[9]);
            } else {
                float* po = h_next + (size_t)i * 16;
                *(float4*)(po)     = make_float4(o[0], o[1], o[2], o[3]);
                *(float4*)(po + 4) = make_float4(o[4], o[5], o[6], o[7]);
                *(float2*)(po + 8) = make_float2(o[8], o[9]);
            }
        }
    }
}

// ---------------- overflow fix-up (expected zero entries) -------------------
__global__ void k_fix(const float* __restrict__ h_cur, float* __restrict__ h_next,
                      const int* __restrict__ ei, int ne,
                      const int* __restrict__ ovf1_cnt, const unsigned* __restrict__ ovf1,
                      const int* __restrict__ ovf2_cnt, const int2* __restrict__ ovf2,
                      const float* __restrict__ w_mp, const float* __restrict__ b_mp,
                      int st) {
    __shared__ float Wa[100], Wb[100], Bm[10];
    int t = threadIdx.x;
    if (t < 100) {
        int k = t / 10, j = t - k * 10;
        float w1 = w_mp[k * 20 + j];
        float w2 = w_mp[k * 20 + 10 + j];
        Wa[t] = w1 - w2; Wb[t] = w2;
    }
    if (t < 10) Bm[t] = b_mp[t];
    __syncthreads();
    int c1 = *ovf1_cnt; if (c1 > OVFN) c1 = OVFN;
    int c2 = *ovf2_cnt; if (c2 > OVFN) c2 = OVFN;
    int gs = gridDim.x * blockDim.x;
    for (int i = blockIdx.x * blockDim.x + t; i < c1 + c2; i += gs) {
        int d, s;
        if (i < c1) {
            unsigned v = ovf1[i];
            if ((int)(v >> 23) != st) continue;
            int idx = (int)(v & 0x7FFFFFu);
            d = ei[idx]; s = ei[(size_t)ne + idx];
        } else {
            int2 p = ovf2[i - c1];
            if ((p.x >> 18) != st) continue;
            d = p.x & 0x3FFFF; s = p.y;
        }
        const float* pi = h_cur + (size_t)d * 16;
        const float* pj = h_cur + (size_t)s * 16;
        float xi[10], xj[10];
        #pragma unroll
        for (int j = 0; j < 10; ++j) { xi[j] = pi[j]; xj[j] = pj[j]; }
        float* po = h_next + (size_t)d * 16;
        #pragma unroll
        for (int k = 0; k < 10; ++k) {
            float m = Bm[k];
            #pragma unroll
            for (int j = 0; j < 10; ++j) m += Wa[k * 10 + j] * xi[j] + Wb[k * 10 + j] * xj[j];
            atomicAdd(po + k, m);
        }
    }
}

__global__ void k_fix_final(const float* __restrict__ h_cur, float* __restrict__ out,
                            const int* __restrict__ ei, int ne,
                            const int* __restrict__ ovf1_cnt, const unsigned* __restrict__ ovf1,
                            const int* __restrict__ ovf2_cnt, const int2* __restrict__ ovf2,
                            const float* __restrict__ w_mp, const float* __restrict__ b_mp,
                            const float* __restrict__ w_out, int st) {
    __shared__ float Wa[100], Wb[100], Bm[10], Wo[100];
    int t = threadIdx.x;
    if (t < 100) {
        int k = t / 10, j = t - k * 10;
        float w1 = w_mp[k * 20 + j];
        float w2 = w_mp[k * 20 + 10 + j];
        Wa[t] = w1 - w2; Wb[t] = w2;
        Wo[t] = w_out[t];
    }
    if (t < 10) Bm[t] = b_mp[t];
    __syncthreads();
    int c1 = *ovf1_cnt; if (c1 > OVFN) c1 = OVFN;
    int c2 = *ovf2_cnt; if (c2 > OVFN) c2 = OVFN;
    int gs = gridDim.x * blockDim.x;
    for (int i = blockIdx.x * blockDim.x + t; i < c1 + c2; i += gs) {
        int d, s;
        if (i < c1) {
            unsigned v = ovf1[i];
            if ((int)(v >> 23) != st) continue;
            int idx = (int)(v & 0x7FFFFFu);
            d = ei[idx]; s = ei[(size_t)ne + idx];
        } else {
            int2 p = ovf2[i - c1];
            if ((p.x >> 18) != st) continue;
            d = p.x & 0x3FFFF; s = p.y;
        }
        const float* pi = h_cur + (size_t)d * 16;
        const float* pj = h_cur + (size_t)s * 16;
        float xi[10], xj[10];
        #pragma unroll
        for (int j = 0; j < 10; ++j) { xi[j] = pi[j]; xj[j] = pj[j]; }
        float dm[10];
        #pragma unroll
        for (int k = 0; k < 10; ++k) {
            float m = Bm[k];
            #pragma unroll
            for (int j = 0; j < 10; ++j) m += Wa[k * 10 + j] * xi[j] + Wb[k * 10 + j] * xj[j];
            dm[k] = m;
        }
        float* po = out + (size_t)d * 10;
        #pragma unroll
        for (int q = 0; q < 10; ++q) {
            float m = 0.0f;
            #pragma unroll
            for (int k = 0; k < 10; ++k) m += Wo[q * 10 + k] * dm[k];
            atomicAdd(po + q, m);
        }
    }
}

// =================== tiny-ws atomic fallback ================================

__global__ void k_init10(const float* __restrict__ x, float* __restrict__ h, int n10) {
    int gs = gridDim.x * blockDim.x;
    for (int i = blockIdx.x * blockDim.x + threadIdx.x; i < n10; i += gs) h[i] = x[i];
}
__global__ void k_copy4(const float4* __restrict__ src, float4* __restrict__ dst, int n4) {
    int gs = gridDim.x * blockDim.x;
    for (int i = blockIdx.x * blockDim.x + threadIdx.x; i < n4; i += gs) dst[i] = src[i];
}
__global__ void k_edge_step10(const float* __restrict__ h_cur, float* __restrict__ h_next,
                              const int* __restrict__ edge_index, const int* __restrict__ order,
                              const float* __restrict__ w_mp, const float* __restrict__ b_mp,
                              int epo, int ne) {
    __shared__ float Wc[200]; __shared__ float Bc[10];
    int t = threadIdx.x;
    if (t < 200) {
        int k = t / 20, j = t - k * 20;
        float w = w_mp[t];
        Wc[t] = (j < 10) ? (w - w_mp[k * 20 + j + 10]) : w;
    }
    if (t < 10) Bc[t] = b_mp[t];
    __syncthreads();
    int gs = gridDim.x * blockDim.x;
    for (int e = blockIdx.x * blockDim.x + t; e < epo; e += gs) {
        int idx = order[e];
        int dst = edge_index[idx];
        int src = edge_index[(size_t)ne + idx];
        const float* pi = h_cur + (size_t)dst * 10;
        const float* pj = h_cur + (size_t)src * 10;
        float xi[10], xj[10];
        #pragma unroll
        for (int j = 0; j < 10; ++j) { xi[j] = pi[j]; xj[j] = pj[j]; }
        float* po = h_next + (size_t)dst * 10;
        #pragma unroll
        for (int k = 0; k < 10; ++k) {
            float m = Bc[k];
            #pragma unroll
            for (int j = 0; j < 10; ++j) m += Wc[k * 20 + j] * xi[j] + Wc[k * 20 + 10 + j] * xj[j];
            atomicAdd(po + k, m);
        }
    }
}
__global__ void k_out10(const float* __restrict__ h, const float* __restrict__ w_out,
                        const float* __restrict__ b_out, float* __restrict__ out, int n) {
    __shared__ float W[100]; __shared__ float B[10];
    int t = threadIdx.x;
    if (t < 100) W[t] = w_out[t];
    if (t < 10)  B[t] = b_out[t];
    __syncthreads();
    int gs = gridDim.x * blockDim.x;
    for (int i = blockIdx.x * blockDim.x + t; i < n; i += gs) {
        float xi[10];
        #pragma unroll
        for (int j = 0; j < 10; ++j) xi[j] = h[(size_t)i * 10 + j];
        #pragma unroll
        for (int k = 0; k < 10; ++k) {
            float m = B[k];
            #pragma unroll
            for (int j = 0; j < 10; ++j) m += W[k * 10 + j] * xi[j];
            out[(size_t)i * 10 + k] = m;
        }
    }
}

// =================== launcher ===================

extern "C" void kernel_launch(void* const* d_in, const int* in_sizes, int n_in,
                              void* d_out, int out_size, void* d_ws, size_t ws_size,
                              hipStream_t stream) {
    const float* x      = (const float*)d_in[0];
    const float* w_mp   = (const float*)d_in[1];
    const float* b_mp   = (const float*)d_in[2];
    const float* w_out  = (const float*)d_in[3];
    const float* b_out  = (const float*)d_in[4];
    const int*   edge_i = (const int*)d_in[5];
    const int*   orders = (const int*)d_in[6];

    int n  = in_sizes[0] / 10;        // 100000
    int ne = in_sizes[5] / 2;         // 6400000
    const int n_orders = 4;
    int epo = in_sizes[6] / n_orders; // 1600000

    float* out = (float*)d_out;

    int NBD = (n + 255) >> 8;                    // 391 dst buckets
    int NW  = (ne + (1 << WBITS) - 1) >> WBITS;  // 782 idx windows
    int NWG = (NW + 3) / 4;                      // 196 window groups
    int TPS = (epo + 512 * IPTA - 1) / (512 * IPTA);  // 196 tiles per step

    // workspace layout (4B elements)
    size_t off_hA    = 0;
    size_t off_hB    = off_hA + (size_t)n * 16;
    size_t off_recs1 = off_hB + (size_t)n * 16;
    size_t off_recs2 = off_recs1 + (size_t)4 * NW * W1CAPS;
    size_t off_ovf2  = off_recs2 + (size_t)4 * NBD * CAPB;   // even offset (int2)
    size_t off_ovf1  = off_ovf2 + (size_t)2 * OVFN;
    size_t off_gcnt1 = off_ovf1 + OVFN;
    size_t off_gcnt2 = off_gcnt1 + (size_t)4 * NW;
    size_t off_cnts  = off_gcnt2 + (size_t)4 * NBD;          // [0]=ovf1, [1]=ovf2
    size_t need      = (off_cnts + 2) * 4;

    bool ok = (ws_size >= need) && (NW <= MAXNW) && (NBD <= MAXNBD) &&
              (ne <= (1 << 23)) && (n < (1 << 17)) && (4 * W1CAPS < 16384);

    if (!ok) {
        // tiny-ws atomic fallback (8 MB)
        float* hA = (float*)d_ws;
        float* hB = hA + (size_t)n * 10;
        int n10 = n * 10;
        hipLaunchKernelGGL(k_init10, dim3(min((n10 + BLK - 1) / BLK, 2048)), dim3(BLK), 0, stream,
                           x, hA, n10);
        int n4 = n10 / 4;
        float* cur = hA; float* nxt = hB;
        int gb_edge = min((epo + BLK - 1) / BLK, 6400);
        for (int s = 0; s < n_orders; ++s) {
            hipLaunchKernelGGL(k_copy4, dim3(min((n4 + BLK - 1) / BLK, 2048)), dim3(BLK), 0, stream,
                               (const float4*)cur, (float4*)nxt, n4);
            hipLaunchKernelGGL(k_edge_step10, dim3(gb_edge), dim3(BLK), 0, stream,
                               cur, nxt, edge_i, orders + (size_t)s * epo, w_mp, b_mp, epo, ne);
            float* t2 = cur; cur = nxt; nxt = t2;
        }
        hipLaunchKernelGGL(k_out10, dim3(min((n + BLK - 1) / BLK, 2048)), dim3(BLK), 0, stream,
                           cur, w_out, b_out, out, n);
        return;
    }

    float*    hA      = (float*)d_ws;
    float*    hB      = (float*)d_ws + off_hB;
    unsigned* recs1   = (unsigned*)d_ws + off_recs1;
    unsigned* recs2   = (unsigned*)d_ws + off_recs2;
    int2*     ovf2    = (int2*)((int*)d_ws + off_ovf2);
    unsigned* ovf1    = (unsigned*)d_ws + off_ovf1;
    int*      gcnt1   = (int*)d_ws + off_gcnt1;
    int*      gcnt2   = (int*)d_ws + off_gcnt2;
    int*      ovfcnts = (int*)d_ws + off_cnts;

    // zero gcnt1 + gcnt2 + ovf counters (contiguous)
    hipMemsetAsync(gcnt1, 0, ((size_t)4 * NW + (size_t)4 * NBD + 2) * sizeof(int), stream);

    int gb_init = min((n * 16 + BLK - 1) / BLK, 2048);
    hipLaunchKernelGGL(k_init_h, dim3(gb_init), dim3(BLK), 0, stream, x, hA, n);

    hipLaunchKernelGGL(k_win, dim3(4 * TPS), dim3(512), 0, stream,
                       orders, epo, NW, TPS, gcnt1, recs1, ovfcnts + 0, ovf1);

    hipLaunchKernelGGL(k_bin2, dim3(4 * NWG), dim3(512), 0, stream,
                       edge_i, ne, gcnt1, recs1, NW, NWG, NBD,
                       gcnt2, recs2, ovfcnts + 1, ovf2);

    float* cur = hA; float* nxt = hB;
    for (int s = 0; s < n_orders; ++s) {
        bool fin = (s == n_orders - 1);
        if (fin) {
            hipLaunchKernelGGL((k_agg2<true>), dim3(NBD), dim3(512), 0, stream,
                               cur, nxt, gcnt2 + (size_t)s * NBD,
                               recs2 + (size_t)s * NBD * CAPB, w_mp, b_mp,
                               w_out, b_out, out, n);
            hipLaunchKernelGGL(k_fix_final, dim3(8), dim3(256), 0, stream,
                               cur, out, edge_i, ne,
                               ovfcnts + 0, ovf1, ovfcnts + 1, ovf2,
                               w_mp, b_mp, w_out, s);
        } else {
            hipLaunchKernelGGL((k_agg2<false>), dim3(NBD), dim3(512), 0, stream,
                               cur, nxt, gcnt2 + (size_t)s * NBD,
                               recs2 + (size_t)s * NBD * CAPB, w_mp, b_mp,
                               w_out, b_out, out, n);
            hipLaunchKernelGGL(k_fix, dim3(8), dim3(256), 0, stream,
                               cur, nxt, edge_i, ne,
                               ovfcnts + 0, ovf1, ovfcnts + 1, ovf2,
                               w_mp, b_mp, s);
            float* t2 = cur; cur = nxt; nxt = t2;
        }
    }
}

// Round 11
// 317.436 us; speedup vs baseline: 1.0241x; 1.0241x over previous
//
#include <hip/hip_runtime.h>

#define BLK 256
#define WBITS 14          // idx-window = 16384 edges (64KB per ei half)
#define W1CAP 17408       // per-window stream cap (mean 16368, +8 sigma) = 17*1024
#define CAPBP 7168        // padded per-(step,dbkt) stream cap (mean ~6490, +8 sigma, 16-mult)
#define MAXNW 512
#define MAXK2 2048
#define MAXNBD 512
#define OVFN 65536
#define IPTA 32           // k_win: 512 thr * 32 = 16384 entries/block
#define NSL2 17           // k_bin2: 1024 thr * 17 = 17408 = W1CAP
#define SENT 0xFFFFFFFFu

// ---------------- init: copy compact x (n,10) into strided h (n,16) --------
__global__ void k_init_h(const float* __restrict__ x, float* __restrict__ h, int n) {
    int total = n * 16;
    int gs = gridDim.x * blockDim.x;
    for (int i = blockIdx.x * blockDim.x + threadIdx.x; i < total; i += gs) {
        int row = i >> 4, col = i & 15;
        h[i] = (col < 10) ? x[row * 10 + col] : 0.0f;
    }
}

// ---------------- pass A: bin order entries by idx-window (mixed-step) -----
// recs1[w][pos] = (st<<23)|idx
__global__ __launch_bounds__(512) void k_win(const int* __restrict__ orders,
                                             int total, int epo, int NW,
                                             int* __restrict__ gcnt1,
                                             unsigned* __restrict__ recs1,
                                             int* __restrict__ ovf1_cnt,
                                             unsigned* __restrict__ ovf1) {
    __shared__ int bcnt[MAXNW];
    __shared__ int gbase[MAXNW];
    int t = threadIdx.x;
    for (int i = t; i < NW; i += 512) bcnt[i] = 0;
    __syncthreads();

    size_t base = (size_t)blockIdx.x * (512 * IPTA);
    int st0 = (int)(base / (size_t)epo);
    size_t b1 = (size_t)(st0 + 1) * (size_t)epo;   // block spans <= one step boundary

    unsigned recr[IPTA]; int rr[IPTA];
    #pragma unroll
    for (int q = 0; q < IPTA; ++q) {
        size_t g = base + (size_t)q * 512 + t;
        recr[q] = SENT; rr[q] = 0;
        if (g < (size_t)total) {
            int idx = orders[g];
            int st = (g >= b1) ? (st0 + 1) : st0;
            recr[q] = ((unsigned)st << 23) | (unsigned)idx;
            rr[q] = atomicAdd(&bcnt[idx >> WBITS], 1);
        }
    }
    __syncthreads();
    for (int k = t; k < NW; k += 512) {
        int c = bcnt[k];
        gbase[k] = c ? atomicAdd(&gcnt1[k], c) : 0;
    }
    __syncthreads();
    #pragma unroll
    for (int q = 0; q < IPTA; ++q) {
        if (recr[q] != SENT) {
            int idx = (int)(recr[q] & 0x7FFFFFu);
            int key = idx >> WBITS;
            int pos = gbase[key] + rr[q];
            if (pos < W1CAP)
                recs1[(size_t)key * W1CAP + pos] = recr[q];
            else {
                int o = atomicAdd(ovf1_cnt, 1);
                if (o < OVFN) ovf1[o] = recr[q];
            }
        }
    }
}

// ---------------- pass B: resolve (d,s) in L2 window, bin by (st, d>>8) ----
// 1 window/block, 1024 thr; LINE-PADDED reservations: each block's run in a
// (st,dbkt) stream is 16-slot (64B) aligned and sentinel-padded -> every
// recs2 line has exactly ONE writer block.
__global__ __launch_bounds__(1024) void k_bin2(const int* __restrict__ ei, int ne,
                                               const int* __restrict__ gcnt1,
                                               const unsigned* __restrict__ recs1,
                                               int NW, int NBD,
                                               int* __restrict__ gcnt2,
                                               unsigned* __restrict__ recs2,
                                               int* __restrict__ ovf2_cnt,
                                               int2* __restrict__ ovf2) {
    __shared__ int cnt2[MAXK2];
    __shared__ int gbase[MAXK2];
    int t = threadIdx.x;
    int K2 = 4 * NBD;
    for (int i = t; i < K2; i += 1024) cnt2[i] = 0;
    __syncthreads();

    int w = blockIdx.x;
    int c = gcnt1[w]; if (c > W1CAP) c = W1CAP;
    const unsigned* strm = recs1 + (size_t)w * W1CAP;

    // 1) independent stream loads
    int recr[NSL2];
    #pragma unroll
    for (int q = 0; q < NSL2; ++q) {
        int r = q * 1024 + t;
        recr[q] = (r < c) ? (int)strm[r] : -1;
    }
    // 2) independent d gathers (64KB window, L2-hot)
    int dv[NSL2];
    #pragma unroll
    for (int q = 0; q < NSL2; ++q)
        dv[q] = (recr[q] >= 0) ? ei[recr[q] & 0x7FFFFF] : 0;
    // 3) LDS rank; meta = (d<<15)|rk  (d<2^17, rk<17408<2^15) — unsigned
    unsigned meta[NSL2];
    #pragma unroll
    for (int q = 0; q < NSL2; ++q) {
        meta[q] = SENT;
        if (recr[q] >= 0) {
            int st = (int)(((unsigned)recr[q]) >> 23);
            int key = st * NBD + (dv[q] >> 8);
            int rk = atomicAdd(&cnt2[key], 1);
            meta[q] = ((unsigned)dv[q] << 15) | (unsigned)rk;
        }
    }
    __syncthreads();
    // 4) line-padded reservation per touched key
    for (int k = t; k < K2; k += 1024) {
        int cc = cnt2[k];
        gbase[k] = cc ? atomicAdd(&gcnt2[k], (cc + 15) & ~15) : 0;
    }
    __syncthreads();
    // 5) gather s + scatter real records
    #pragma unroll
    for (int q = 0; q < NSL2; ++q) {
        if (meta[q] != SENT) {
            int idx = recr[q] & 0x7FFFFF;
            int st  = (int)(((unsigned)recr[q]) >> 23);
            int s = ei[(size_t)ne + idx];           // 64KB window
            int d = (int)(meta[q] >> 15);
            int rk = (int)(meta[q] & 0x7FFFu);
            int key = st * NBD + (d >> 8);
            int pos = gbase[key] + rk;
            unsigned r2 = ((unsigned)(d & 255) << 20) | (unsigned)s;
            if (pos < CAPBP)
                recs2[(size_t)key * CAPBP + pos] = r2;
            else {
                int o = atomicAdd(ovf2_cnt, 1);
                if (o < OVFN) ovf2[o] = make_int2((st << 18) | d, s);
            }
        }
    }
    // 6) sentinel-fill pad slots (keeps lines single-writer, marks invalid)
    for (int k = t; k < K2; k += 1024) {
        int cc = cnt2[k];
        if (cc) {
            int b0 = gbase[k];
            int pe = b0 + ((cc + 15) & ~15);
            if (pe > CAPBP) pe = CAPBP;
            unsigned* sp = recs2 + (size_t)k * CAPBP;
            for (int p = b0 + cc; p < pe; ++p) sp[p] = SENT;
        }
    }
}

// ---------------- aggregate via in-LDS counting sort, register sums --------
#define IPTG ((CAPBP + 511) / 512)    // 14
template<bool FINAL>
__global__ __launch_bounds__(512) void k_agg2(const float* __restrict__ h_cur,
                                              float* __restrict__ h_next,
                                              const int* __restrict__ gcnt2_st,
                                              const unsigned* __restrict__ recs2_st,
                                              const float* __restrict__ w_mp,
                                              const float* __restrict__ b_mp,
                                              const float* __restrict__ w_out,
                                              const float* __restrict__ b_out,
                                              float* __restrict__ out, int n) {
    __shared__ unsigned srt[CAPBP];
    __shared__ int cnts[256];
    __shared__ int sc[256];
    __shared__ int offs[257];
    __shared__ float part[256 * 10];
    __shared__ float Wa[100], Wb[100], Bm[10];
    __shared__ float Wo[100], Bo[10];
    int t = threadIdx.x;
    if (t < 100) {
        int k = t / 10, j = t - k * 10;
        float w1 = w_mp[k * 20 + j];
        float w2 = w_mp[k * 20 + 10 + j];
        Wa[t] = w1 - w2; Wb[t] = w2;
        if (FINAL) Wo[t] = w_out[t];
    }
    if (t < 10) { Bm[t] = b_mp[t]; if (FINAL) Bo[t] = b_out[t]; }
    if (t < 256) cnts[t] = 0;
    __syncthreads();

    int bkt = blockIdx.x;
    int cnt = gcnt2_st[bkt];
    if (cnt > CAPBP) cnt = CAPBP;
    const unsigned* strm = recs2_st + (size_t)bkt * CAPBP;

    // stage to registers (static slots) + histogram; skip sentinels
    unsigned myrec[IPTG];
    #pragma unroll
    for (int q = 0; q < IPTG; ++q) {
        int r = q * 512 + t;
        myrec[q] = SENT;
        if (r < cnt) {
            unsigned rec = strm[r];
            if (rec != SENT) {
                myrec[q] = rec;
                atomicAdd(&cnts[rec >> 20], 1);
            }
        }
    }
    __syncthreads();

    if (t < 256) sc[t] = cnts[t];
    __syncthreads();
    for (int off = 1; off < 256; off <<= 1) {
        int v = (t < 256 && t >= off) ? sc[t - off] : 0;
        __syncthreads();
        if (t < 256) sc[t] += v;
        __syncthreads();
    }
    if (t < 256) offs[t + 1] = sc[t];
    if (t == 0) offs[0] = 0;
    __syncthreads();
    if (t < 256) cnts[t] = offs[t];
    __syncthreads();

    #pragma unroll
    for (int q = 0; q < IPTG; ++q) {
        if (myrec[q] != SENT) {
            int pos = atomicAdd(&cnts[myrec[q] >> 20], 1);
            srt[pos] = myrec[q];
        }
    }
    __syncthreads();

    int node = t & 255, half = t >> 8;
    int b0 = offs[node], m = offs[node + 1] - b0;
    float S[10] = {0,0,0,0,0,0,0,0,0,0};
    for (int p = b0 + half; p < b0 + m; p += 2) {
        int s = (int)(srt[p] & 0xFFFFFu);
        const float* pj = h_cur + (size_t)s * 16;
        float4 a0 = *(const float4*)(pj);
        float4 a1 = *(const float4*)(pj + 4);
        float2 a2 = *(const float2*)(pj + 8);
        S[0] += a0.x; S[1] += a0.y; S[2] += a0.z; S[3] += a0.w;
        S[4] += a1.x; S[5] += a1.y; S[6] += a1.z; S[7] += a1.w;
        S[8] += a2.x; S[9] += a2.y;
    }
    if (half == 1) {
        #pragma unroll
        for (int j = 0; j < 10; ++j) part[node * 10 + j] = S[j];
    }
    __syncthreads();
    if (half == 0) {
        int i = bkt * 256 + node;
        if (i < n) {
            #pragma unroll
            for (int j = 0; j < 10; ++j) S[j] += part[node * 10 + j];
            const float* pi = h_cur + (size_t)i * 16;
            float4 x0 = *(const float4*)(pi);
            float4 x1 = *(const float4*)(pi + 4);
            float2 x2 = *(const float2*)(pi + 8);
            float xi[10] = {x0.x, x0.y, x0.z, x0.w, x1.x, x1.y, x1.z, x1.w, x2.x, x2.y};
            float deg = (float)m;
            float o[10];
            #pragma unroll
            for (int k = 0; k < 10; ++k) {
                float ma = Bm[k];
                float mb = 0.0f;
                #pragma unroll
                for (int j = 0; j < 10; ++j) {
                    ma += Wa[k * 10 + j] * xi[j];
                    mb += Wb[k * 10 + j] * S[j];
                }
                o[k] = xi[k] + deg * ma + mb;
            }
            if (FINAL) {
                float q2[10];
                #pragma unroll
                for (int k = 0; k < 10; ++k) {
                    float m2 = Bo[k];
                    #pragma unroll
                    for (int j = 0; j < 10; ++j) m2 += Wo[k * 10 + j] * o[j];
                    q2[k] = m2;
                }
                float* po = out + (size_t)i * 10;
                *(float2*)(po)     = make_float2(q2[0], q2[1]);
                *(float2*)(po + 2) = make_float2(q2[2], q2[3]);
                *(float2*)(po + 4) = make_float2(q2[4], q2[5]);
                *(float2*)(po + 6) = make_float2(q2[6], q2[7]);
                *(float2*)(po + 8) = make_float2(q2[8], q2[9]);
            } else {
                float* po = h_next + (size_t)i * 16;
                *(float4*)(po)     = make_float4(o[0], o[1], o[2], o[3]);
                *(float4*)(po + 4) = make_float4(o[4], o[5], o[6], o[7]);
                *(float2*)(po + 8) = make_float2(o[8], o[9]);
            }
        }
    }
}

// ---------------- overflow fix-up (expected zero entries) -------------------
__global__ void k_fix(const float* __restrict__ h_cur, float* __restrict__ h_next,
                      const int* __restrict__ ei, int ne,
                      const int* __restrict__ ovf1_cnt, const unsigned* __restrict__ ovf1,
                      const int* __restrict__ ovf2_cnt, const int2* __restrict__ ovf2,
                      const float* __restrict__ w_mp, const float* __restrict__ b_mp,
                      int st) {
    __shared__ float Wa[100], Wb[100], Bm[10];
    int t = threadIdx.x;
    if (t < 100) {
        int k = t / 10, j = t - k * 10;
        float w1 = w_mp[k * 20 + j];
        float w2 = w_mp[k * 20 + 10 + j];
        Wa[t] = w1 - w2; Wb[t] = w2;
    }
    if (t < 10) Bm[t] = b_mp[t];
    __syncthreads();
    int c1 = *ovf1_cnt; if (c1 > OVFN) c1 = OVFN;
    int c2 = *ovf2_cnt; if (c2 > OVFN) c2 = OVFN;
    int gs = gridDim.x * blockDim.x;
    for (int i = blockIdx.x * blockDim.x + t; i < c1 + c2; i += gs) {
        int d, s;
        if (i < c1) {
            unsigned v = ovf1[i];
            if ((int)(v >> 23) != st) continue;
            int idx = (int)(v & 0x7FFFFFu);
            d = ei[idx]; s = ei[(size_t)ne + idx];
        } else {
            int2 p = ovf2[i - c1];
            if ((p.x >> 18) != st) continue;
            d = p.x & 0x3FFFF; s = p.y;
        }
        const float* pi = h_cur + (size_t)d * 16;
        const float* pj = h_cur + (size_t)s * 16;
        float xi[10], xj[10];
        #pragma unroll
        for (int j = 0; j < 10; ++j) { xi[j] = pi[j]; xj[j] = pj[j]; }
        float* po = h_next + (size_t)d * 16;
        #pragma unroll
        for (int k = 0; k < 10; ++k) {
            float m = Bm[k];
            #pragma unroll
            for (int j = 0; j < 10; ++j) m += Wa[k * 10 + j] * xi[j] + Wb[k * 10 + j] * xj[j];
            atomicAdd(po + k, m);
        }
    }
}

__global__ void k_fix_final(const float* __restrict__ h_cur, float* __restrict__ out,
                            const int* __restrict__ ei, int ne,
                            const int* __restrict__ ovf1_cnt, const unsigned* __restrict__ ovf1,
                            const int* __restrict__ ovf2_cnt, const int2* __restrict__ ovf2,
                            const float* __restrict__ w_mp, const float* __restrict__ b_mp,
                            const float* __restrict__ w_out, int st) {
    __shared__ float Wa[100], Wb[100], Bm[10], Wo[100];
    int t = threadIdx.x;
    if (t < 100) {
        int k = t / 10, j = t - k * 10;
        float w1 = w_mp[k * 20 + j];
        float w2 = w_mp[k * 20 + 10 + j];
        Wa[t] = w1 - w2; Wb[t] = w2;
        Wo[t] = w_out[t];
    }
    if (t < 10) Bm[t] = b_mp[t];
    __syncthreads();
    int c1 = *ovf1_cnt; if (c1 > OVFN) c1 = OVFN;
    int c2 = *ovf2_cnt; if (c2 > OVFN) c2 = OVFN;
    int gs = gridDim.x * blockDim.x;
    for (int i = blockIdx.x * blockDim.x + t; i < c1 + c2; i += gs) {
        int d, s;
        if (i < c1) {
            unsigned v = ovf1[i];
            if ((int)(v >> 23) != st) continue;
            int idx = (int)(v & 0x7FFFFFu);
            d = ei[idx]; s = ei[(size_t)ne + idx];
        } else {
            int2 p = ovf2[i - c1];
            if ((p.x >> 18) != st) continue;
            d = p.x & 0x3FFFF; s = p.y;
        }
        const float* pi = h_cur + (size_t)d * 16;
        const float* pj = h_cur + (size_t)s * 16;
        float xi[10], xj[10];
        #pragma unroll
        for (int j = 0; j < 10; ++j) { xi[j] = pi[j]; xj[j] = pj[j]; }
        float dm[10];
        #pragma unroll
        for (int k = 0; k < 10; ++k) {
            float m = Bm[k];
            #pragma unroll
            for (int j = 0; j < 10; ++j) m += Wa[k * 10 + j] * xi[j] + Wb[k * 10 + j] * xj[j];
            dm[k] = m;
        }
        float* po = out + (size_t)d * 10;
        #pragma unroll
        for (int q = 0; q < 10; ++q) {
            float m = 0.0f;
            #pragma unroll
            for (int k = 0; k < 10; ++k) m += Wo[q * 10 + k] * dm[k];
            atomicAdd(po + q, m);
        }
    }
}

// =================== tiny-ws atomic fallback ================================

__global__ void k_init10(const float* __restrict__ x, float* __restrict__ h, int n10) {
    int gs = gridDim.x * blockDim.x;
    for (int i = blockIdx.x * blockDim.x + threadIdx.x; i < n10; i += gs) h[i] = x[i];
}
__global__ void k_copy4(const float4* __restrict__ src, float4* __restrict__ dst, int n4) {
    int gs = gridDim.x * blockDim.x;
    for (int i = blockIdx.x * blockDim.x + threadIdx.x; i < n4; i += gs) dst[i] = src[i];
}
__global__ void k_edge_step10(const float* __restrict__ h_cur, float* __restrict__ h_next,
                              const int* __restrict__ edge_index, const int* __restrict__ order,
                              const float* __restrict__ w_mp, const float* __restrict__ b_mp,
                              int epo, int ne) {
    __shared__ float Wc[200]; __shared__ float Bc[10];
    int t = threadIdx.x;
    if (t < 200) {
        int k = t / 20, j = t - k * 20;
        float w = w_mp[t];
        Wc[t] = (j < 10) ? (w - w_mp[k * 20 + j + 10]) : w;
    }
    if (t < 10) Bc[t] = b_mp[t];
    __syncthreads();
    int gs = gridDim.x * blockDim.x;
    for (int e = blockIdx.x * blockDim.x + t; e < epo; e += gs) {
        int idx = order[e];
        int dst = edge_index[idx];
        int src = edge_index[(size_t)ne + idx];
        const float* pi = h_cur + (size_t)dst * 10;
        const float* pj = h_cur + (size_t)src * 10;
        float xi[10], xj[10];
        #pragma unroll
        for (int j = 0; j < 10; ++j) { xi[j] = pi[j]; xj[j] = pj[j]; }
        float* po = h_next + (size_t)dst * 10;
        #pragma unroll
        for (int k = 0; k < 10; ++k) {
            float m = Bc[k];
            #pragma unroll
            for (int j = 0; j < 10; ++j) m += Wc[k * 20 + j] * xi[j] + Wc[k * 20 + 10 + j] * xj[j];
            atomicAdd(po + k, m);
        }
    }
}
__global__ void k_out10(const float* __restrict__ h, const float* __restrict__ w_out,
                        const float* __restrict__ b_out, float* __restrict__ out, int n) {
    __shared__ float W[100]; __shared__ float B[10];
    int t = threadIdx.x;
    if (t < 100) W[t] = w_out[t];
    if (t < 10)  B[t] = b_out[t];
    __syncthreads();
    int gs = gridDim.x * blockDim.x;
    for (int i = blockIdx.x * blockDim.x + t; i < n; i += gs) {
        float xi[10];
        #pragma unroll
        for (int j = 0; j < 10; ++j) xi[j] = h[(size_t)i * 10 + j];
        #pragma unroll
        for (int k = 0; k < 10; ++k) {
            float m = B[k];
            #pragma unroll
            for (int j = 0; j < 10; ++j) m += W[k * 10 + j] * xi[j];
            out[(size_t)i * 10 + k] = m;
        }
    }
}

// =================== launcher ===================

extern "C" void kernel_launch(void* const* d_in, const int* in_sizes, int n_in,
                              void* d_out, int out_size, void* d_ws, size_t ws_size,
                              hipStream_t stream) {
    const float* x      = (const float*)d_in[0];
    const float* w_mp   = (const float*)d_in[1];
    const float* b_mp   = (const float*)d_in[2];
    const float* w_out  = (const float*)d_in[3];
    const float* b_out  = (const float*)d_in[4];
    const int*   edge_i = (const int*)d_in[5];
    const int*   orders = (const int*)d_in[6];

    int n  = in_sizes[0] / 10;        // 100000
    int ne = in_sizes[5] / 2;         // 6400000
    const int n_orders = 4;
    int epo = in_sizes[6] / n_orders; // 1600000
    int total = n_orders * epo;

    float* out = (float*)d_out;

    int NBD = (n + 255) >> 8;                    // 391 dst buckets
    int NW  = (ne + (1 << WBITS) - 1) >> WBITS;  // 391 idx windows
    int K2  = 4 * NBD;

    // workspace layout (4B elements)
    size_t off_hA    = 0;
    size_t off_hB    = off_hA + (size_t)n * 16;
    size_t off_recs1 = off_hB + (size_t)n * 16;
    size_t off_recs2 = off_recs1 + (size_t)NW * W1CAP;       // 64B-aligned streams
    size_t off_ovf2  = off_recs2 + (size_t)K2 * CAPBP;       // even offset (int2)
    size_t off_ovf1  = off_ovf2 + (size_t)2 * OVFN;
    size_t off_gcnt1 = off_ovf1 + OVFN;
    size_t off_gcnt2 = off_gcnt1 + NW;
    size_t off_cnts  = off_gcnt2 + K2;                       // [0]=ovf1, [1]=ovf2
    size_t need      = (off_cnts + 2) * 4;

    bool ok = (ws_size >= need) && (NW <= MAXNW) && (NBD <= MAXNBD) &&
              (K2 <= MAXK2) && (ne <= (1 << 23)) && (n < (1 << 17));

    if (!ok) {
        // tiny-ws atomic fallback (8 MB)
        float* hA = (float*)d_ws;
        float* hB = hA + (size_t)n * 10;
        int n10 = n * 10;
        hipLaunchKernelGGL(k_init10, dim3(min((n10 + BLK - 1) / BLK, 2048)), dim3(BLK), 0, stream,
                           x, hA, n10);
        int n4 = n10 / 4;
        float* cur = hA; float* nxt = hB;
        int gb_edge = min((epo + BLK - 1) / BLK, 6400);
        for (int s = 0; s < n_orders; ++s) {
            hipLaunchKernelGGL(k_copy4, dim3(min((n4 + BLK - 1) / BLK, 2048)), dim3(BLK), 0, stream,
                               (const float4*)cur, (float4*)nxt, n4);
            hipLaunchKernelGGL(k_edge_step10, dim3(gb_edge), dim3(BLK), 0, stream,
                               cur, nxt, edge_i, orders + (size_t)s * epo, w_mp, b_mp, epo, ne);
            float* t2 = cur; cur = nxt; nxt = t2;
        }
        hipLaunchKernelGGL(k_out10, dim3(min((n + BLK - 1) / BLK, 2048)), dim3(BLK), 0, stream,
                           cur, w_out, b_out, out, n);
        return;
    }

    float*    hA      = (float*)d_ws;
    float*    hB      = (float*)d_ws + off_hB;
    unsigned* recs1   = (unsigned*)d_ws + off_recs1;
    unsigned* recs2   = (unsigned*)d_ws + off_recs2;
    int2*     ovf2    = (int2*)((int*)d_ws + off_ovf2);
    unsigned* ovf1    = (unsigned*)d_ws + off_ovf1;
    int*      gcnt1   = (int*)d_ws + off_gcnt1;
    int*      gcnt2   = (int*)d_ws + off_gcnt2;
    int*      ovfcnts = (int*)d_ws + off_cnts;

    // zero gcnt1 + gcnt2 + ovf counters (contiguous)
    hipMemsetAsync(gcnt1, 0, ((size_t)NW + (size_t)K2 + 2) * sizeof(int), stream);

    int gb_init = min((n * 16 + BLK - 1) / BLK, 2048);
    hipLaunchKernelGGL(k_init_h, dim3(gb_init), dim3(BLK), 0, stream, x, hA, n);

    int gbA = (total + 512 * IPTA - 1) / (512 * IPTA);   // 391
    hipLaunchKernelGGL(k_win, dim3(gbA), dim3(512), 0, stream,
                       orders, total, epo, NW, gcnt1, recs1, ovfcnts + 0, ovf1);

    hipLaunchKernelGGL(k_bin2, dim3(NW), dim3(1024), 0, stream,
                       edge_i, ne, gcnt1, recs1, NW, NBD,
                       gcnt2, recs2, ovfcnts + 1, ovf2);

    float* cur = hA; float* nxt = hB;
    for (int s = 0; s < n_orders; ++s) {
        bool fin = (s == n_orders - 1);
        if (fin) {
            hipLaunchKernelGGL((k_agg2<true>), dim3(NBD), dim3(512), 0, stream,
                               cur, nxt, gcnt2 + (size_t)s * NBD,
                               recs2 + (size_t)s * NBD * CAPBP, w_mp, b_mp,
                               w_out, b_out, out, n);
            hipLaunchKernelGGL(k_fix_final, dim3(8), dim3(256), 0, stream,
                               cur, out, edge_i, ne,
                               ovfcnts + 0, ovf1, ovfcnts + 1, ovf2,
                               w_mp, b_mp, w_out, s);
        } else {
            hipLaunchKernelGGL((k_agg2<false>), dim3(NBD), dim3(512), 0, stream,
                               cur, nxt, gcnt2 + (size_t)s * NBD,
                               recs2 + (size_t)s * NBD * CAPBP, w_mp, b_mp,
                               w_out, b_out, out, n);
            hipLaunchKernelGGL(k_fix, dim3(8), dim3(256), 0, stream,
                               cur, nxt, edge_i, ne,
                               ovfcnts + 0, ovf1, ovfcnts + 1, ovf2,
                               w_mp, b_mp, s);
            float* t2 = cur; cur = nxt; nxt = t2;
        }
    }
}

// Round 12
// 287.310 us; speedup vs baseline: 1.1315x; 1.1049x over previous
//
#include <hip/hip_runtime.h>

#define BLK 256
#define WBITS 13          // idx-window = 8192 edges (32KB per ei half)
#define W1CAP 9216        // per-window stream cap (mean 8184, +11 sigma) = 18*512
#define STCAP 4608        // per-(step,dbkt) staging cap (mean 4092, +8 sigma)
#define MAXNW 1024
#define MAXK2 2048
#define MAXNBD 512
#define OVFN 65536
#define IPTA 32           // k_win: 512 thr * 32 = 16384 entries/block
#define NSL 18            // k_bsort: 512 thr * 18 = 9216 = W1CAP
#define SENT 0xFFFFFFFFu

// ---------------- init: copy compact x (n,10) into strided h (n,16) --------
__global__ void k_init_h(const float* __restrict__ x, float* __restrict__ h, int n) {
    int total = n * 16;
    int gs = gridDim.x * blockDim.x;
    for (int i = blockIdx.x * blockDim.x + threadIdx.x; i < total; i += gs) {
        int row = i >> 4, col = i & 15;
        h[i] = (col < 10) ? x[row * 10 + col] : 0.0f;
    }
}

// ---------------- pass A: bin order entries by idx-window (mixed-step) -----
// recs1[w][pos] = (st<<23)|idx
__global__ __launch_bounds__(512) void k_win(const int* __restrict__ orders,
                                             int total, int epo, int NW,
                                             int* __restrict__ gcnt1,
                                             unsigned* __restrict__ recs1,
                                             int* __restrict__ ovf1_cnt,
                                             unsigned* __restrict__ ovf1) {
    __shared__ int bcnt[MAXNW];
    __shared__ int gbase[MAXNW];
    int t = threadIdx.x;
    for (int i = t; i < NW; i += 512) bcnt[i] = 0;
    __syncthreads();

    size_t base = (size_t)blockIdx.x * (512 * IPTA);
    int st0 = (int)(base / (size_t)epo);
    size_t b1 = (size_t)(st0 + 1) * (size_t)epo;   // block spans <= one step boundary

    unsigned recr[IPTA]; int rr[IPTA];
    #pragma unroll
    for (int q = 0; q < IPTA; ++q) {
        size_t g = base + (size_t)q * 512 + t;
        recr[q] = SENT; rr[q] = 0;
        if (g < (size_t)total) {
            int idx = orders[g];
            int st = (g >= b1) ? (st0 + 1) : st0;
            recr[q] = ((unsigned)st << 23) | (unsigned)idx;
            rr[q] = atomicAdd(&bcnt[idx >> WBITS], 1);
        }
    }
    __syncthreads();
    for (int k = t; k < NW; k += 512) {
        int c = bcnt[k];
        gbase[k] = c ? atomicAdd(&gcnt1[k], c) : 0;
    }
    __syncthreads();
    #pragma unroll
    for (int q = 0; q < IPTA; ++q) {
        if (recr[q] != SENT) {
            int idx = (int)(recr[q] & 0x7FFFFFu);
            int key = idx >> WBITS;
            int pos = gbase[key] + rr[q];
            if (pos < W1CAP)
                recs1[(size_t)key * W1CAP + pos] = recr[q];
            else {
                int o = atomicAdd(ovf1_cnt, 1);
                if (o < OVFN) ovf1[o] = recr[q];
            }
        }
    }
}

// ---------------- pass B: resolve (d,s), LOCAL counting sort, coalesced dump
// Output: recs2[w*W1CAP ..] = block's records sorted by key=(st,d>>8);
//         blk_offs[w][k] = exclusive offsets (k in [0,K2]).
// NO scattered global stores, no per-key caps, no overflow.
__global__ __launch_bounds__(512) void k_bsort(const int* __restrict__ ei, int ne,
                                               const int* __restrict__ gcnt1,
                                               const unsigned* __restrict__ recs1,
                                               int NW, int NBD, int K2,
                                               unsigned* __restrict__ recs2,
                                               int* __restrict__ blk_offs) {
    __shared__ unsigned srt[W1CAP];     // 36 KB
    __shared__ int cnt2[MAXK2];         // histogram (K2 used)
    __shared__ int lofs[MAXK2 + 1];     // exclusive offsets
    __shared__ int sc[512];
    int t = threadIdx.x;
    for (int i = t; i < K2; i += 512) cnt2[i] = 0;
    __syncthreads();

    int w = blockIdx.x;
    int c = gcnt1[w]; if (c > W1CAP) c = W1CAP;
    const unsigned* strm = recs1 + (size_t)w * W1CAP;

    // 1) independent stream loads
    int recr[NSL];
    #pragma unroll
    for (int q = 0; q < NSL; ++q) {
        int r = q * 512 + t;
        recr[q] = (r < c) ? (int)strm[r] : -1;
    }
    // 2) independent d gathers (32KB window, L1/L2-hot)
    int dv[NSL];
    #pragma unroll
    for (int q = 0; q < NSL; ++q)
        dv[q] = (recr[q] >= 0) ? ei[recr[q] & 0x7FFFFF] : 0;
    // 3) LDS rank; meta = (d<<14)|rk (d<2^17, rk small)
    unsigned meta[NSL];
    #pragma unroll
    for (int q = 0; q < NSL; ++q) {
        meta[q] = SENT;
        if (recr[q] >= 0) {
            int st = (int)(((unsigned)recr[q]) >> 23);
            int key = st * NBD + (dv[q] >> 8);
            int rk = atomicAdd(&cnt2[key], 1);
            meta[q] = ((unsigned)dv[q] << 14) | (unsigned)rk;
        }
    }
    __syncthreads();

    // 4) exclusive scan of cnt2[0..K2) -> lofs[0..K2]
    {
        int v[4]; int sum = 0;
        #pragma unroll
        for (int i = 0; i < 4; ++i) {
            int k = t * 4 + i;
            v[i] = (k < K2) ? cnt2[k] : 0;
            sum += v[i];
        }
        sc[t] = sum;
        __syncthreads();
        for (int off = 1; off < 512; off <<= 1) {
            int u = (t >= off) ? sc[t - off] : 0;
            __syncthreads();
            sc[t] += u;
            __syncthreads();
        }
        int run = sc[t] - sum;
        #pragma unroll
        for (int i = 0; i < 4; ++i) {
            int k = t * 4 + i;
            if (k <= K2) lofs[k] = run;
            run += v[i];
        }
        if (t == 511) lofs[K2] = sc[511];   // ensure total present
    }
    __syncthreads();

    // 5) gather s + scatter into LDS sorted order
    #pragma unroll
    for (int q = 0; q < NSL; ++q) {
        if (meta[q] != SENT) {
            int idx = recr[q] & 0x7FFFFF;
            int st  = (int)(((unsigned)recr[q]) >> 23);
            int s = ei[(size_t)ne + idx];
            int d = (int)(meta[q] >> 14);
            int rk = (int)(meta[q] & 0x3FFFu);
            int key = st * NBD + (d >> 8);
            srt[lofs[key] + rk] = ((unsigned)(d & 255) << 20) | (unsigned)s;
        }
    }
    __syncthreads();

    // 6) coalesced dump of sorted records + offsets
    unsigned* dst = recs2 + (size_t)w * W1CAP;
    for (int r = t; r < c; r += 512) dst[r] = srt[r];
    int* bo = blk_offs + (size_t)w * (K2 + 1);
    for (int k = t; k <= K2; k += 512) bo[k] = lofs[k];
}

// ---------------- aggregate: segmented gather -> LDS sort -> register sums --
template<bool FINAL>
__global__ __launch_bounds__(512) void k_agg3(const float* __restrict__ h_cur,
                                              float* __restrict__ h_next,
                                              const int* __restrict__ blk_offs,
                                              const unsigned* __restrict__ recs2,
                                              int NW, int K2, int NBD, int st,
                                              const float* __restrict__ w_mp,
                                              const float* __restrict__ b_mp,
                                              const float* __restrict__ w_out,
                                              const float* __restrict__ b_out,
                                              float* __restrict__ out, int n,
                                              int* __restrict__ ovf2_cnt,
                                              int2* __restrict__ ovf2) {
    __shared__ unsigned stage[STCAP];
    __shared__ unsigned srt[STCAP];
    __shared__ int cnts[256];
    __shared__ int sc[256];
    __shared__ int offs[257];
    __shared__ int cursor;
    __shared__ float part[256 * 10];
    __shared__ float Wa[100], Wb[100], Bm[10];
    __shared__ float Wo[100], Bo[10];
    int t = threadIdx.x;
    if (t < 100) {
        int k = t / 10, j = t - k * 10;
        float w1 = w_mp[k * 20 + j];
        float w2 = w_mp[k * 20 + 10 + j];
        Wa[t] = w1 - w2; Wb[t] = w2;
        if (FINAL) Wo[t] = w_out[t];
    }
    if (t < 10) { Bm[t] = b_mp[t]; if (FINAL) Bo[t] = b_out[t]; }
    if (t < 256) cnts[t] = 0;
    if (t == 0) cursor = 0;
    __syncthreads();

    int bkt = blockIdx.x;
    int key = st * NBD + bkt;

    // Phase A: gather segments from every bin-block, stage + histogram
    for (int b = t; b < NW; b += 512) {
        const int* bo = blk_offs + (size_t)b * (K2 + 1) + key;
        int o0 = bo[0], o1 = bo[1];
        int len = o1 - o0;
        if (len > 0) {
            int base = atomicAdd(&cursor, len);
            const unsigned* src = recs2 + (size_t)b * W1CAP + o0;
            for (int i = 0; i < len; ++i) {
                unsigned rec = src[i];
                int pos = base + i;
                if (pos < STCAP) {
                    stage[pos] = rec;
                    atomicAdd(&cnts[rec >> 20], 1);
                } else {
                    int o = atomicAdd(ovf2_cnt, 1);
                    if (o < OVFN)
                        ovf2[o] = make_int2((st << 18) | (bkt * 256 + (int)(rec >> 20)),
                                            (int)(rec & 0xFFFFFu));
                }
            }
        }
    }
    __syncthreads();
    int T = cursor; if (T > STCAP) T = STCAP;

    // exclusive scan of cnts -> offs
    if (t < 256) sc[t] = cnts[t];
    __syncthreads();
    for (int off = 1; off < 256; off <<= 1) {
        int v = (t < 256 && t >= off) ? sc[t - off] : 0;
        __syncthreads();
        if (t < 256) sc[t] += v;
        __syncthreads();
    }
    if (t < 256) offs[t + 1] = sc[t];
    if (t == 0) offs[0] = 0;
    __syncthreads();
    if (t < 256) cnts[t] = offs[t];     // cursor per node
    __syncthreads();

    // Phase C: scatter into sorted order
    for (int r = t; r < T; r += 512) {
        unsigned rec = stage[r];
        int pos = atomicAdd(&cnts[rec >> 20], 1);
        srt[pos] = rec;
    }
    __syncthreads();

    // Phase D: per-node gather-sum, 2 threads per node
    int node = t & 255, half = t >> 8;
    int b0 = offs[node], m = offs[node + 1] - b0;
    float S[10] = {0,0,0,0,0,0,0,0,0,0};
    for (int p = b0 + half; p < b0 + m; p += 2) {
        int s = (int)(srt[p] & 0xFFFFFu);
        const float* pj = h_cur + (size_t)s * 16;
        float4 a0 = *(const float4*)(pj);
        float4 a1 = *(const float4*)(pj + 4);
        float2 a2 = *(const float2*)(pj + 8);
        S[0] += a0.x; S[1] += a0.y; S[2] += a0.z; S[3] += a0.w;
        S[4] += a1.x; S[5] += a1.y; S[6] += a1.z; S[7] += a1.w;
        S[8] += a2.x; S[9] += a2.y;
    }
    if (half == 1) {
        #pragma unroll
        for (int j = 0; j < 10; ++j) part[node * 10 + j] = S[j];
    }
    __syncthreads();
    if (half == 0) {
        int i = bkt * 256 + node;
        if (i < n) {
            #pragma unroll
            for (int j = 0; j < 10; ++j) S[j] += part[node * 10 + j];
            const float* pi = h_cur + (size_t)i * 16;
            float4 x0 = *(const float4*)(pi);
            float4 x1 = *(const float4*)(pi + 4);
            float2 x2 = *(const float2*)(pi + 8);
            float xi[10] = {x0.x, x0.y, x0.z, x0.w, x1.x, x1.y, x1.z, x1.w, x2.x, x2.y};
            float deg = (float)m;
            float o[10];
            #pragma unroll
            for (int k = 0; k < 10; ++k) {
                float ma = Bm[k];
                float mb = 0.0f;
                #pragma unroll
                for (int j = 0; j < 10; ++j) {
                    ma += Wa[k * 10 + j] * xi[j];
                    mb += Wb[k * 10 + j] * S[j];
                }
                o[k] = xi[k] + deg * ma + mb;
            }
            if (FINAL) {
                float q2[10];
                #pragma unroll
                for (int k = 0; k < 10; ++k) {
                    float m2 = Bo[k];
                    #pragma unroll
                    for (int j = 0; j < 10; ++j) m2 += Wo[k * 10 + j] * o[j];
                    q2[k] = m2;
                }
                float* po = out + (size_t)i * 10;
                *(float2*)(po)     = make_float2(q2[0], q2[1]);
                *(float2*)(po + 2) = make_float2(q2[2], q2[3]);
                *(float2*)(po + 4) = make_float2(q2[4], q2[5]);
                *(float2*)(po + 6) = make_float2(q2[6], q2[7]);
                *(float2*)(po + 8) = make_float2(q2[8], q2[9]);
            } else {
                float* po = h_next + (size_t)i * 16;
                *(float4*)(po)     = make_float4(o[0], o[1], o[2], o[3]);
                *(float4*)(po + 4) = make_float4(o[4], o[5], o[6], o[7]);
                *(float2*)(po + 8) = make_float2(o[8], o[9]);
            }
        }
    }
}

// ---------------- overflow fix-up (expected zero entries) -------------------
__global__ void k_fix(const float* __restrict__ h_cur, float* __restrict__ h_next,
                      const int* __restrict__ ei, int ne,
                      const int* __restrict__ ovf1_cnt, const unsigned* __restrict__ ovf1,
                      const int* __restrict__ ovf2_cnt, const int2* __restrict__ ovf2,
                      const float* __restrict__ w_mp, const float* __restrict__ b_mp,
                      int st) {
    __shared__ float Wa[100], Wb[100], Bm[10];
    int t = threadIdx.x;
    if (t < 100) {
        int k = t / 10, j = t - k * 10;
        float w1 = w_mp[k * 20 + j];
        float w2 = w_mp[k * 20 + 10 + j];
        Wa[t] = w1 - w2; Wb[t] = w2;
    }
    if (t < 10) Bm[t] = b_mp[t];
    __syncthreads();
    int c1 = *ovf1_cnt; if (c1 > OVFN) c1 = OVFN;
    int c2 = *ovf2_cnt; if (c2 > OVFN) c2 = OVFN;
    int gs = gridDim.x * blockDim.x;
    for (int i = blockIdx.x * blockDim.x + t; i < c1 + c2; i += gs) {
        int d, s;
        if (i < c1) {
            unsigned v = ovf1[i];
            if ((int)(v >> 23) != st) continue;
            int idx = (int)(v & 0x7FFFFFu);
            d = ei[idx]; s = ei[(size_t)ne + idx];
        } else {
            int2 p = ovf2[i - c1];
            if ((p.x >> 18) != st) continue;
            d = p.x & 0x3FFFF; s = p.y;
        }
        const float* pi = h_cur + (size_t)d * 16;
        const float* pj = h_cur + (size_t)s * 16;
        float xi[10], xj[10];
        #pragma unroll
        for (int j = 0; j < 10; ++j) { xi[j] = pi[j]; xj[j] = pj[j]; }
        float* po = h_next + (size_t)d * 16;
        #pragma unroll
        for (int k = 0; k < 10; ++k) {
            float m = Bm[k];
            #pragma unroll
            for (int j = 0; j < 10; ++j) m += Wa[k * 10 + j] * xi[j] + Wb[k * 10 + j] * xj[j];
            atomicAdd(po + k, m);
        }
    }
}

__global__ void k_fix_final(const float* __restrict__ h_cur, float* __restrict__ out,
                            const int* __restrict__ ei, int ne,
                            const int* __restrict__ ovf1_cnt, const unsigned* __restrict__ ovf1,
                            const int* __restrict__ ovf2_cnt, const int2* __restrict__ ovf2,
                            const float* __restrict__ w_mp, const float* __restrict__ b_mp,
                            const float* __restrict__ w_out, int st) {
    __shared__ float Wa[100], Wb[100], Bm[10], Wo[100];
    int t = threadIdx.x;
    if (t < 100) {
        int k = t / 10, j = t - k * 10;
        float w1 = w_mp[k * 20 + j];
        float w2 = w_mp[k * 20 + 10 + j];
        Wa[t] = w1 - w2; Wb[t] = w2;
        Wo[t] = w_out[t];
    }
    if (t < 10) Bm[t] = b_mp[t];
    __syncthreads();
    int c1 = *ovf1_cnt; if (c1 > OVFN) c1 = OVFN;
    int c2 = *ovf2_cnt; if (c2 > OVFN) c2 = OVFN;
    int gs = gridDim.x * blockDim.x;
    for (int i = blockIdx.x * blockDim.x + t; i < c1 + c2; i += gs) {
        int d, s;
        if (i < c1) {
            unsigned v = ovf1[i];
            if ((int)(v >> 23) != st) continue;
            int idx = (int)(v & 0x7FFFFFu);
            d = ei[idx]; s = ei[(size_t)ne + idx];
        } else {
            int2 p = ovf2[i - c1];
            if ((p.x >> 18) != st) continue;
            d = p.x & 0x3FFFF; s = p.y;
        }
        const float* pi = h_cur + (size_t)d * 16;
        const float* pj = h_cur + (size_t)s * 16;
        float xi[10], xj[10];
        #pragma unroll
        for (int j = 0; j < 10; ++j) { xi[j] = pi[j]; xj[j] = pj[j]; }
        float dm[10];
        #pragma unroll
        for (int k = 0; k < 10; ++k) {
            float m = Bm[k];
            #pragma unroll
            for (int j = 0; j < 10; ++j) m += Wa[k * 10 + j] * xi[j] + Wb[k * 10 + j] * xj[j];
            dm[k] = m;
        }
        float* po = out + (size_t)d * 10;
        #pragma unroll
        for (int q = 0; q < 10; ++q) {
            float m = 0.0f;
            #pragma unroll
            for (int k = 0; k < 10; ++k) m += Wo[q * 10 + k] * dm[k];
            atomicAdd(po + q, m);
        }
    }
}

// =================== tiny-ws atomic fallback ================================

__global__ void k_init10(const float* __restrict__ x, float* __restrict__ h, int n10) {
    int gs = gridDim.x * blockDim.x;
    for (int i = blockIdx.x * blockDim.x + threadIdx.x; i < n10; i += gs) h[i] = x[i];
}
__global__ void k_copy4(const float4* __restrict__ src, float4* __restrict__ dst, int n4) {
    int gs = gridDim.x * blockDim.x;
    for (int i = blockIdx.x * blockDim.x + threadIdx.x; i < n4; i += gs) dst[i] = src[i];
}
__global__ void k_edge_step10(const float* __restrict__ h_cur, float* __restrict__ h_next,
                              const int* __restrict__ edge_index, const int* __restrict__ order,
                              const float* __restrict__ w_mp, const float* __restrict__ b_mp,
                              int epo, int ne) {
    __shared__ float Wc[200]; __shared__ float Bc[10];
    int t = threadIdx.x;
    if (t < 200) {
        int k = t / 20, j = t - k * 20;
        float w = w_mp[t];
        Wc[t] = (j < 10) ? (w - w_mp[k * 20 + j + 10]) : w;
    }
    if (t < 10) Bc[t] = b_mp[t];
    __syncthreads();
    int gs = gridDim.x * blockDim.x;
    for (int e = blockIdx.x * blockDim.x + t; e < epo; e += gs) {
        int idx = order[e];
        int dst = edge_index[idx];
        int src = edge_index[(size_t)ne + idx];
        const float* pi = h_cur + (size_t)dst * 10;
        const float* pj = h_cur + (size_t)src * 10;
        float xi[10], xj[10];
        #pragma unroll
        for (int j = 0; j < 10; ++j) { xi[j] = pi[j]; xj[j] = pj[j]; }
        float* po = h_next + (size_t)dst * 10;
        #pragma unroll
        for (int k = 0; k < 10; ++k) {
            float m = Bc[k];
            #pragma unroll
            for (int j = 0; j < 10; ++j) m += Wc[k * 20 + j] * xi[j] + Wc[k * 20 + 10 + j] * xj[j];
            atomicAdd(po + k, m);
        }
    }
}
__global__ void k_out10(const float* __restrict__ h, const float* __restrict__ w_out,
                        const float* __restrict__ b_out, float* __restrict__ out, int n) {
    __shared__ float W[100]; __shared__ float B[10];
    int t = threadIdx.x;
    if (t < 100) W[t] = w_out[t];
    if (t < 10)  B[t] = b_out[t];
    __syncthreads();
    int gs = gridDim.x * blockDim.x;
    for (int i = blockIdx.x * blockDim.x + t; i < n; i += gs) {
        float xi[10];
        #pragma unroll
        for (int j = 0; j < 10; ++j) xi[j] = h[(size_t)i * 10 + j];
        #pragma unroll
        for (int k = 0; k < 10; ++k) {
            float m = B[k];
            #pragma unroll
            for (int j = 0; j < 10; ++j) m += W[k * 10 + j] * xi[j];
            out[(size_t)i * 10 + k] = m;
        }
    }
}

// =================== launcher ===================

extern "C" void kernel_launch(void* const* d_in, const int* in_sizes, int n_in,
                              void* d_out, int out_size, void* d_ws, size_t ws_size,
                              hipStream_t stream) {
    const float* x      = (const float*)d_in[0];
    const float* w_mp   = (const float*)d_in[1];
    const float* b_mp   = (const float*)d_in[2];
    const float* w_out  = (const float*)d_in[3];
    const float* b_out  = (const float*)d_in[4];
    const int*   edge_i = (const int*)d_in[5];
    const int*   orders = (const int*)d_in[6];

    int n  = in_sizes[0] / 10;        // 100000
    int ne = in_sizes[5] / 2;         // 6400000
    const int n_orders = 4;
    int epo = in_sizes[6] / n_orders; // 1600000
    int total = n_orders * epo;

    float* out = (float*)d_out;

    int NBD = (n + 255) >> 8;                    // 391 dst buckets
    int NW  = (ne + (1 << WBITS) - 1) >> WBITS;  // 782 idx windows
    int K2  = 4 * NBD;                           // 1564

    // workspace layout (4B elements)
    size_t off_hA    = 0;
    size_t off_hB    = off_hA + (size_t)n * 16;
    size_t off_recs1 = off_hB + (size_t)n * 16;
    size_t off_recs2 = off_recs1 + (size_t)NW * W1CAP;
    size_t off_boffs = off_recs2 + (size_t)NW * W1CAP;
    size_t off_ovf2  = off_boffs + (size_t)NW * (K2 + 1);
    if (off_ovf2 & 1) off_ovf2++;                            // int2 align
    size_t off_ovf1  = off_ovf2 + (size_t)2 * OVFN;
    size_t off_gcnt1 = off_ovf1 + OVFN;
    size_t off_cnts  = off_gcnt1 + NW;                       // [0]=ovf1, [1]=ovf2
    size_t need      = (off_cnts + 2) * 4;

    bool ok = (ws_size >= need) && (NW <= MAXNW) && (NBD <= MAXNBD) &&
              (K2 <= MAXK2) && (ne <= (1 << 23)) && (n < (1 << 17));

    if (!ok) {
        // tiny-ws atomic fallback (8 MB)
        float* hA = (float*)d_ws;
        float* hB = hA + (size_t)n * 10;
        int n10 = n * 10;
        hipLaunchKernelGGL(k_init10, dim3(min((n10 + BLK - 1) / BLK, 2048)), dim3(BLK), 0, stream,
                           x, hA, n10);
        int n4 = n10 / 4;
        float* cur = hA; float* nxt = hB;
        int gb_edge = min((epo + BLK - 1) / BLK, 6400);
        for (int s = 0; s < n_orders; ++s) {
            hipLaunchKernelGGL(k_copy4, dim3(min((n4 + BLK - 1) / BLK, 2048)), dim3(BLK), 0, stream,
                               (const float4*)cur, (float4*)nxt, n4);
            hipLaunchKernelGGL(k_edge_step10, dim3(gb_edge), dim3(BLK), 0, stream,
                               cur, nxt, edge_i, orders + (size_t)s * epo, w_mp, b_mp, epo, ne);
            float* t2 = cur; cur = nxt; nxt = t2;
        }
        hipLaunchKernelGGL(k_out10, dim3(min((n + BLK - 1) / BLK, 2048)), dim3(BLK), 0, stream,
                           cur, w_out, b_out, out, n);
        return;
    }

    float*    hA      = (float*)d_ws;
    float*    hB      = (float*)d_ws + off_hB;
    unsigned* recs1   = (unsigned*)d_ws + off_recs1;
    unsigned* recs2   = (unsigned*)d_ws + off_recs2;
    int*      boffs   = (int*)d_ws + off_boffs;
    int2*     ovf2    = (int2*)((int*)d_ws + off_ovf2);
    unsigned* ovf1    = (unsigned*)d_ws + off_ovf1;
    int*      gcnt1   = (int*)d_ws + off_gcnt1;
    int*      ovfcnts = (int*)d_ws + off_cnts;

    // zero gcnt1 + ovf counters (contiguous)
    hipMemsetAsync(gcnt1, 0, ((size_t)NW + 2) * sizeof(int), stream);

    int gb_init = min((n * 16 + BLK - 1) / BLK, 2048);
    hipLaunchKernelGGL(k_init_h, dim3(gb_init), dim3(BLK), 0, stream, x, hA, n);

    int gbA = (total + 512 * IPTA - 1) / (512 * IPTA);   // 391
    hipLaunchKernelGGL(k_win, dim3(gbA), dim3(512), 0, stream,
                       orders, total, epo, NW, gcnt1, recs1, ovfcnts + 0, ovf1);

    hipLaunchKernelGGL(k_bsort, dim3(NW), dim3(512), 0, stream,
                       edge_i, ne, gcnt1, recs1, NW, NBD, K2, recs2, boffs);

    float* cur = hA; float* nxt = hB;
    for (int s = 0; s < n_orders; ++s) {
        bool fin = (s == n_orders - 1);
        if (fin) {
            hipLaunchKernelGGL((k_agg3<true>), dim3(NBD), dim3(512), 0, stream,
                               cur, nxt, boffs, recs2, NW, K2, NBD, s,
                               w_mp, b_mp, w_out, b_out, out, n,
                               ovfcnts + 1, ovf2);
            hipLaunchKernelGGL(k_fix_final, dim3(8), dim3(256), 0, stream,
                               cur, out, edge_i, ne,
                               ovfcnts + 0, ovf1, ovfcnts + 1, ovf2,
                               w_mp, b_mp, w_out, s);
        } else {
            hipLaunchKernelGGL((k_agg3<false>), dim3(NBD), dim3(512), 0, stream,
                               cur, nxt, boffs, recs2, NW, K2, NBD, s,
                               w_mp, b_mp, w_out, b_out, out, n,
                               ovfcnts + 1, ovf2);
            hipLaunchKernelGGL(k_fix, dim3(8), dim3(256), 0, stream,
                               cur, nxt, edge_i, ne,
                               ovfcnts + 0, ovf1, ovfcnts + 1, ovf2,
                               w_mp, b_mp, s);
            float* t2 = cur; cur = nxt; nxt = t2;
        }
    }
}